// Round 19
// baseline (43.388 us; speedup 1.0000x reference)
//
#include <hip/hip_runtime.h>

// APLoss (r2d2 QAPLoss). B=2, H=W=32 -> N=M=1024/batch, D=128, 25 bins.
// u = 24*(1-sim); cumsum_k of triangular bins = clamp(k+1-u, 0, 1).
// R19 = R14/R17 champion (25.6us) with boundary-bin histogram:
// each element touches at most ONE fractional bin -> per-thread LDS scatter
// (H[bin][tid], ds_add_f32, bank = tid%32 -> conflict-free, zero contention)
// replaces the 25-bin register sweep + DPP reduce.
//   k_main : S0 tile (8q x 1024p ping-pong GEMM on desc2) -> on-the-fly
//            bilinear warp + scatter-hist + AP  (256 blk x 512 thr)
//   k_final: 256 partials -> out.

#define NQB 25

// ---- sim helpers: chunk = 8 consecutive c (verbatim champion) --------------
__device__ __forceinline__ void loadc(const float* __restrict__ dp, int ch,
                                      float* d)
{
    int cb = ch << 3;
#pragma unroll
    for (int i = 0; i < 8; i++) {
        d[i]     = dp[(size_t)(cb + i) << 10];           // p = tid
        d[8 + i] = dp[(((size_t)(cb + i)) << 10) + 512]; // p = tid + 512
    }
}
__device__ __forceinline__ void fmac(const float* __restrict__ d1, int ch,
                                     const float* d, float* a0, float* a1)
{
    int cb = ch << 3;
#pragma unroll
    for (int i = 0; i < 8; i++) {
        const float* qp = d1 + ((size_t)(cb + i) << 10);
#pragma unroll
        for (int qq = 0; qq < 8; qq++) {
            float qv = qp[qq];   // wave-uniform -> scalar load
            a0[qq] = fmaf(qv, d[i], a0[qq]);
            a1[qq] = fmaf(qv, d[8 + i], a1[qq]);
        }
    }
}

// ---- K1: fused S0 GEMM + warp + scatter-hist + AP; 8 q x all m, 512 thr ----
__global__ __launch_bounds__(512) void k_main(const float* __restrict__ desc1,
                                              const float* __restrict__ desc2,
                                              const float* __restrict__ grd,
                                              const int* __restrict__ label,
                                              float* __restrict__ appart)
{
    __shared__ float s[8][1024];   // S0 tile: 8 queries x 1024 grid positions
    __shared__ float H[52][512];   // rows 0..25: E_cn bins; 26..51: E_cr bins
    __shared__ float Eb[8][52];    // per-query bin sums
    __shared__ float apb[8];

    int tid = threadIdx.x;
    int qg0 = blockIdx.x << 3;      // global query base (b*1024 + n0)
    int b = qg0 >> 10;
    int n0 = qg0 & 1023;

    // ---- zero the scatter histogram (covered by the post-GEMM barrier) ----
    {
        float4 z4; z4.x = 0.f; z4.y = 0.f; z4.z = 0.f; z4.w = 0.f;
        float4* hz = (float4*)&H[0][0];   // 52*512/4 = 6656 float4
#pragma unroll
        for (int i = 0; i < 13; i++) hz[(i << 9) + tid] = z4;
    }

    // ---- prefetch labels + grid coords for my 16 m's (hide under GEMM) ----
    int q = tid >> 6, l = tid & 63; // hist roles: wave = query, lane = l
    const int* lp = label + ((size_t)(qg0 + q) << 10) + l;
    int lv[16];
#pragma unroll
    for (int e = 0; e < 16; e++) lv[e] = lp[(size_t)(e << 6)];
    const float2* gp = (const float2*)grd + ((size_t)b << 10) + l;
    float2 gv[16];
#pragma unroll
    for (int e = 0; e < 16; e++) gv[e] = gp[(size_t)(e << 6)];

    // ---- S0 GEMM phase: 2-deep ping-pong over 16 chunks of 8 c ----
    const float* d1 = desc1 + ((size_t)b << 17) + n0;  // q-row: d1[(c<<10)+qq]
    const float* dp = desc2 + ((size_t)b << 17) + tid; // p-col: dp[c<<10]

    float a0[8], a1[8];
#pragma unroll
    for (int qq = 0; qq < 8; qq++) { a0[qq] = 0.f; a1[qq] = 0.f; }

    float dA[16], dB[16];
    loadc(dp, 0, dA);
    for (int ch = 0; ch < 16; ch += 2) {
        loadc(dp, ch + 1, dB);          // issue next chunk
        fmac(d1, ch, dA, a0, a1);       // consume current
        if (ch + 2 < 16) loadc(dp, ch + 2, dA);
        fmac(d1, ch + 1, dB, a0, a1);
    }
#pragma unroll
    for (int qq = 0; qq < 8; qq++) { s[qq][tid] = a0[qq]; s[qq][tid + 512] = a1[qq]; }
    __syncthreads();

    // ---- scatter histogram with on-the-fly bilinear warp (champion gather) -
    const float* sq = s[q];
    float* Hc = &H[0][tid];         // my private column, stride 512
#pragma unroll
    for (int e = 0; e < 16; e++) {
        float gx = gv[e].x, gy = gv[e].y;
        float fx = ((gx + 1.f) * 32.f - 1.f) * 0.5f;
        float fy = ((gy + 1.f) * 32.f - 1.f) * 0.5f;
        float x0f = floorf(fx), y0f = floorf(fy);
        float wx1 = fx - x0f, wy1 = fy - y0f;
        float wx0 = 1.f - wx1, wy0 = 1.f - wy1;
        int x0 = (int)x0f, y0 = (int)y0f;
        int x1 = x0 + 1, y1 = y0 + 1;
        bool bx0 = (unsigned)x0 < 32u, bx1 = (unsigned)x1 < 32u;
        bool by0 = (unsigned)y0 < 32u, by1 = (unsigned)y1 < 32u;
        float w00 = (by0 && bx0) ? wy0 * wx0 : 0.f;
        float w01 = (by0 && bx1) ? wy0 * wx1 : 0.f;
        float w10 = (by1 && bx0) ? wy1 * wx0 : 0.f;
        float w11 = (by1 && bx1) ? wy1 * wx1 : 0.f;
        int xc0 = min(max(x0, 0), 31), xc1 = min(max(x1, 0), 31);
        int yc0 = min(max(y0, 0), 31), yc1 = min(max(y1, 0), 31);
        float sv = w00 * sq[(yc0 << 5) + xc0];
        sv = fmaf(w01, sq[(yc0 << 5) + xc1], sv);
        sv = fmaf(w10, sq[(yc1 << 5) + xc0], sv);
        sv = fmaf(w11, sq[(yc1 << 5) + xc1], sv);

        // boundary-bin decomposition: at most 2 touched bins per element
        float u = fmaxf(fmaf(-24.f, sv, 24.f), 0.f);
        int ku = (int)u;                       // floor, u >= 0
        float frac = (float)(ku + 1) - u;      // in (0, 1]
        if (ku <= 24) {
            atomicAdd(&Hc[(size_t)(ku << 9)], frac);                 // E_cn[ku]
            if (lv[e]) atomicAdd(&Hc[(size_t)((26 + ku) << 9)], frac);
        }
        if (ku <= 23) {
            float g = 1.f - frac;
            atomicAdd(&Hc[(size_t)((ku + 1) << 9)], g);              // E_cn[ku+1]
            if (lv[e]) atomicAdd(&Hc[(size_t)((27 + ku) << 9)], g);
        }
    }
    __syncthreads();

    // ---- per-(query, bin) column sums: 416 threads, float4 reads ----
    if (tid < 416) {
        int q2 = tid / 52, j = tid - q2 * 52;
        const float4* row = (const float4*)&H[j][q2 << 6];
        float ssum = 0.f;
#pragma unroll
        for (int i = 0; i < 16; i++) {
            float4 v4 = row[i];
            ssum += v4.x + v4.y + v4.z + v4.w;
        }
        Eb[q2][j] = ssum;
    }
    __syncthreads();

    // ---- AP per query (8 threads, running prefix), block sum -> 1 float ----
    if (tid < 8) {
        float ap = 0.f, prev = 0.f, cn = 0.f, cr = 0.f;
#pragma unroll
        for (int k = 0; k < NQB; k++) {
            cn += Eb[tid][k];
            cr += Eb[tid][26 + k];
            float pr = cr / (1e-16f + cn);
            ap += pr * (cr - prev);
            prev = cr;
        }
        apb[tid] = ap / prev;
    }
    __syncthreads();
    if (tid == 0) {
        float v = 0.f;
#pragma unroll
        for (int q2 = 0; q2 < 8; q2++) v += apb[q2];
        appart[blockIdx.x] = v;
    }
}

// ---- K2: final reduce of per-block sums -> d_out ---------------------------
__global__ __launch_bounds__(256) void k_final(const float* __restrict__ appart,
                                               float* __restrict__ out,
                                               int nb, float invn)
{
    int tid = threadIdx.x;
    float v = 0.f;
    for (int i = tid; i < nb; i += 256) v += appart[i];
    for (int off = 32; off; off >>= 1) v += __shfl_xor(v, off, 64);
    __shared__ float wsum[4];
    if ((tid & 63) == 0) wsum[tid >> 6] = v;
    __syncthreads();
    if (tid == 0) out[0] = (wsum[0] + wsum[1] + wsum[2] + wsum[3]) * invn;
}

extern "C" void kernel_launch(void* const* d_in, const int* in_sizes, int n_in,
                              void* d_out, int out_size, void* d_ws, size_t ws_size,
                              hipStream_t stream)
{
    const float* desc1 = (const float*)d_in[0];
    const float* desc2 = (const float*)d_in[1];
    // d_in[2] = reliability: unused by the reference output
    const float* grd   = (const float*)d_in[3];
    const int*   label = (const int*)d_in[4];

    int B = in_sizes[0] / (128 * 1024);
    int npos = B * 1024;
    int nblk = npos / 8;

    float* ws = (float*)d_ws;
    float* appart = ws;                 // nblk floats
    float* out = (float*)d_out;

    k_main<<<nblk, 512, 0, stream>>>(desc1, desc2, grd, label, appart);
    k_final<<<1, 256, 0, stream>>>(appart, out, nblk, 1.f / (float)npos);
}